// Round 11
// baseline (67.155 us; speedup 1.0000x reference)
//
#include <hip/hip_runtime.h>

typedef __attribute__((ext_vector_type(8))) __bf16 bf16x8;
typedef __attribute__((ext_vector_type(4))) float f32x4;

#define M_ 256
#define N_ 4096
#define K_ 4096
#define SPLITK 2
#define KC (K_ / SPLITK)   // 2048
#define BM 128
#define BN 64
#define BK 32
#define KSTEPS (KC / BK)   // 64
#define NCH 20             // 1KB chunks per K-step: A_hi 8 | A_lo 8 | B 4
#define LDSBUF 20480       // NCH KB

// Tiled operand layout: 1KB bf16 tile = 16 rows x 32 k; tile(rt,kt) index
// rt*128+kt; slot lane = (row&15)+16*((k>>3)&3), elem = k&7.
// Producers iterate in OUTPUT order (thread = 16B slot) so writes coalesce;
// every global_load_lds reads one contiguous 1KB (lane*16B), zero scatter.

// ---------- helpers ----------

__device__ __forceinline__ unsigned short f2bf(float f) {
  unsigned int u = __builtin_bit_cast(unsigned int, f);
  u += 0x7fffu + ((u >> 16) & 1u);
  return (unsigned short)(u >> 16);
}

__device__ __forceinline__ void async16(const void* g, void* l) {
  __builtin_amdgcn_global_load_lds(
      (const __attribute__((address_space(1))) unsigned int*)g,
      (__attribute__((address_space(3))) unsigned int*)l, 16, 0, 0);
}

__device__ __forceinline__ float lsq1(float y, float a, float s) {
  float yc = fminf(fmaxf(y, -a), a);
  return rintf(yc / s) * s;
}

// ---------- K1: fused producer (R7 verbatim) ----------
// blocks [0, NQB): lattice-quantize W -> zq (bf16 bits, tiled slot order).
//   z dot: f32 UNFUSED mul+add, sequential ascending — bit-matches XLA:CPU ref.
//   DO NOT TOUCH the arithmetic (verified absmax 0.0117, rounds 3-8).
// blocks [NQB, NQB+NXB): xg = x_blocks @ G^T -> bf16 hi/lo (tiled layout).

#define NQB ((N_ * K_ / 8) / 256)  // 8192
#define NXB ((M_ * K_ / 8) / 256)  // 512

__global__ __launch_bounds__(256) void k_prep(const float* __restrict__ W,
                                              const float* __restrict__ theta,
                                              const float* __restrict__ Ginv,
                                              const float* __restrict__ x,
                                              const float* __restrict__ G,
                                              unsigned short* __restrict__ zq,
                                              unsigned short* __restrict__ hi,
                                              unsigned short* __restrict__ lo,
                                              int kTheta) {
  __shared__ float Ms[64];
  const int tid = threadIdx.x;
  const bool isQ = blockIdx.x < NQB;
  if (tid < 64) Ms[tid] = isQ ? Ginv[tid] : G[tid];
  __syncthreads();

  if (isQ) {
    const int s = blockIdx.x * 256 + tid;       // output 16B slot
    const int lane6 = s & 63;
    const int tile = s >> 6;
    const int o  = ((tile >> 7) << 4) + (lane6 & 15);   // W row
    const int kb = ((tile & 127) << 2) + (lane6 >> 4);  // 8-elt k-block
    const float4* wp = (const float4*)(W + ((size_t)o << 12) + ((size_t)kb << 3));
    const float4 w0 = wp[0], w1 = wp[1];
    float sc = 0.f;
    for (int t = 0; t < kTheta; ++t) sc += theta[o * kTheta + t];
    sc /= (float)kTheta;
    const float wsv[8] = {w0.x * sc, w0.y * sc, w0.z * sc, w0.w * sc,
                          w1.x * sc, w1.y * sc, w1.z * sc, w1.w * sc};
    unsigned int packed[4] = {0u, 0u, 0u, 0u};
    const unsigned long long lut = 0x3F800000BF80C000ull;  // idx 0..3 -> -2,-1,0,+1 (bf16)
#pragma unroll
    for (int i = 0; i < 8; ++i) {
      float t = 0.f;
#pragma unroll
      for (int j = 0; j < 8; ++j)
        t = __fadd_rn(t, __fmul_rn(wsv[j], Ms[j * 8 + i]));  // unfused, sequential
      const int zi = (int)rintf(t);
      const int idx = (zi + 2) & 3;
      const unsigned int h = (unsigned int)((lut >> (idx * 16)) & 0xFFFFull);
      packed[i >> 1] |= h << ((i & 1) * 16);
    }
    *(uint4*)(zq + ((size_t)s << 3)) = make_uint4(packed[0], packed[1], packed[2], packed[3]);
  } else {
    const int s = (blockIdx.x - NQB) * 256 + tid;
    const int lane6 = s & 63;
    const int tile = s >> 6;
    const int m  = ((tile >> 7) << 4) + (lane6 & 15);
    const int kb = ((tile & 127) << 2) + (lane6 >> 4);
    const float4* xp = (const float4*)(x + ((size_t)m << 12) + ((size_t)kb << 3));
    const float4 a0 = xp[0], a1 = xp[1];
    float xv[8] = {a0.x, a0.y, a0.z, a0.w, a1.x, a1.y, a1.z, a1.w};
    unsigned int ph[4] = {0u, 0u, 0u, 0u}, pl[4] = {0u, 0u, 0u, 0u};
#pragma unroll
    for (int i = 0; i < 8; ++i) {
      float t = 0.f;
#pragma unroll
      for (int j = 0; j < 8; ++j) t = fmaf(xv[j], Ms[i * 8 + j], t);
      const unsigned short hb = f2bf(t);
      const float hf = __builtin_bit_cast(float, (unsigned int)hb << 16);
      const unsigned short lb = f2bf(t - hf);
      ph[i >> 1] |= ((unsigned int)hb) << ((i & 1) * 16);
      pl[i >> 1] |= ((unsigned int)lb) << ((i & 1) * 16);
    }
    *(uint4*)(hi + ((size_t)s << 3)) = make_uint4(ph[0], ph[1], ph[2], ph[3]);
    *(uint4*)(lo + ((size_t)s << 3)) = make_uint4(pl[0], pl[1], pl[2], pl[3]);
  }
}

// ---------- K2: split-K GEMM (R7 structure verbatim; SPLITK=2) ----------
// 512 thr = 8 waves (4m x 2n), tile 128x64, BK=32, 2-barrier double buffer,
// contiguous-1KB global_load_lds staging for A and B (zq bf16).
// Per-accumulator MFMA k-order: ascending k32, hi-then-lo (verified r3-r8).

__global__ __launch_bounds__(512, 4) void k_gemm(const unsigned short* __restrict__ xgh,
                                                 const unsigned short* __restrict__ xgl,
                                                 const unsigned short* __restrict__ z,
                                                 float* __restrict__ part) {
  __shared__ uint4 smem4[2 * LDSBUF / 16];  // 40KB double buffer
  char* smem = (char*)smem4;

  const int tid = threadIdx.x;
  const int lane = tid & 63, wave = tid >> 6;
  const int wr = wave >> 1, wc = wave & 1;   // wave grid 4m x 2n
  const int b = blockIdx.x;
  const int mt = b & 1;
  const int sk = (b >> 1) & 1;
  const int nt = b >> 2;                     // 0..63
  const int k0t = sk * (KC / 32);            // base k-tile index (0 or 64)
  const int rowa16 = mt * (BM / 16);
  const int rowb16 = nt * (BN / 16);
  const int lrow = lane & 15, lkg = lane >> 4;

  // 20 chunks: c 0..7 = A_hi tile c, 8..15 = A_lo tile c-8, 16..19 = B tile c-16.
  // wave w stages chunks {w, w+8, w+16 (w<4 only)}.
  const unsigned short* src[3];
  unsigned int ldso[3];
#pragma unroll
  for (int ci = 0; ci < 3; ++ci) {
    const int c = ci * 8 + wave;
    if (c < NCH) {
      const unsigned short* P;
      int rt;
      if (c < 8)       { P = xgh; rt = rowa16 + c; }
      else if (c < 16) { P = xgl; rt = rowa16 + (c - 8); }
      else             { P = z;   rt = rowb16 + (c - 16); }
      src[ci] = P + (((size_t)(rt * 128 + k0t)) << 9) + lane * 8;
      ldso[ci] = (unsigned int)c * 1024u;
    } else {
      src[ci] = nullptr;
      ldso[ci] = 0;
    }
  }
  const int nchunk = (wave < 4) ? 3 : 2;

  f32x4 acc[2][2] = {};

  // prologue: stage step 0 into buffer 0
  for (int ci = 0; ci < nchunk; ++ci) async16(src[ci], smem + ldso[ci]);
  __syncthreads();

  for (int ks = 0; ks < KSTEPS; ++ks) {
    const int cur = (ks & 1) * LDSBUF;
    const int nxt = LDSBUF - cur;
    if (ks + 1 < KSTEPS) {
      for (int ci = 0; ci < nchunk; ++ci)
        async16(src[ci] + (size_t)(ks + 1) * 512, smem + nxt + ldso[ci]);
    }

    bf16x8 bfr[2], ah[2], al[2];
#pragma unroll
    for (int nf = 0; nf < 2; ++nf)
      bfr[nf] = *(const bf16x8*)(smem + cur + (16 + wc * 2 + nf) * 1024 + lane * 16);
#pragma unroll
    for (int mf = 0; mf < 2; ++mf) {
      ah[mf] = *(const bf16x8*)(smem + cur + (wr * 2 + mf) * 1024 + lane * 16);
      al[mf] = *(const bf16x8*)(smem + cur + (8 + wr * 2 + mf) * 1024 + lane * 16);
    }
#pragma unroll
    for (int mf = 0; mf < 2; ++mf)
#pragma unroll
      for (int nf = 0; nf < 2; ++nf) {
        acc[mf][nf] = __builtin_amdgcn_mfma_f32_16x16x32_bf16(ah[mf], bfr[nf], acc[mf][nf], 0, 0, 0);
        acc[mf][nf] = __builtin_amdgcn_mfma_f32_16x16x32_bf16(al[mf], bfr[nf], acc[mf][nf], 0, 0, 0);
      }
    __syncthreads();  // drains vmcnt(0)+lgkmcnt(0): stage above targets NEXT buffer
  }

  // C/D layout (m89-verified): col = lane&15, row = (lane>>4)*4 + reg
  float* pb = part + (size_t)sk * (M_ * N_);
  const int row_a = mt * BM, row_b = nt * BN;
#pragma unroll
  for (int mf = 0; mf < 2; ++mf)
#pragma unroll
    for (int nf = 0; nf < 2; ++nf)
#pragma unroll
      for (int r = 0; r < 4; ++r) {
        const int m = row_a + wr * 32 + mf * 16 + lkg * 4 + r;
        const int n = row_b + wc * 32 + nf * 16 + lrow;
        pb[(size_t)m * N_ + n] = acc[mf][nf][r];
      }
}

// ---------- K3: reduce 2 split-K partials + bias + LSQ epilogue ----------

__global__ __launch_bounds__(256) void k_epi(const float* __restrict__ part,
                                             const float* __restrict__ bias,
                                             const float* __restrict__ alpha,
                                             float* __restrict__ out) {
  const int i4 = blockIdx.x * 256 + threadIdx.x;  // over M_*N_/4
  const size_t off = (size_t)i4 * 4;
  const float4 p0 = *(const float4*)(part + off);
  const float4 p1 = *(const float4*)(part + (size_t)1 * M_ * N_ + off);
  const int n = (int)(off & (N_ - 1));
  const float4 bv = *(const float4*)(bias + n);
  const float a = fmaxf(alpha[0], 0.f) + 1e-8f;
  const float s = a / 127.0f;
  float4 o;
  o.x = lsq1((p0.x + p1.x) + bv.x, a, s);
  o.y = lsq1((p0.y + p1.y) + bv.y, a, s);
  o.z = lsq1((p0.z + p1.z) + bv.z, a, s);
  o.w = lsq1((p0.w + p1.w) + bv.w, a, s);
  *(float4*)(out + off) = o;
}

// ---------- launch ----------

extern "C" void kernel_launch(void* const* d_in, const int* in_sizes, int n_in,
                              void* d_out, int out_size, void* d_ws, size_t ws_size,
                              hipStream_t stream) {
  const float* x     = (const float*)d_in[0];
  const float* W     = (const float*)d_in[1];
  const float* bias  = (const float*)d_in[2];
  const float* theta = (const float*)d_in[3];
  const float* alpha = (const float*)d_in[4];
  const float* G     = (const float*)d_in[5];
  const float* Ginv  = (const float*)d_in[6];
  float* out = (float*)d_out;

  const int O = in_sizes[2];           // 4096
  const int kTheta = in_sizes[3] / O;  // 1

  // ws layout: zq bf16 tiled 32MB | xg_hi 2MB | xg_lo 2MB | partials [2][M][N] 8MB
  char* ws = (char*)d_ws;
  unsigned short* zq  = (unsigned short*)ws;
  unsigned short* xgh = (unsigned short*)(ws + 33554432);
  unsigned short* xgl = (unsigned short*)(ws + 35651584);
  float* part = (float*)(ws + 37748736);
  if (ws_size < 46137344) return;  // guard: need 44MB scratch

  k_prep<<<NQB + NXB, 256, 0, stream>>>(W, theta, Ginv, x, G, zq, xgh, xgl, kTheta);
  k_gemm<<<2 * SPLITK * 64, 512, 0, stream>>>(xgh, xgl, zq, part);
  k_epi<<<(M_ * N_ / 4) / 256, 256, 0, stream>>>(part, bias, alpha, out);
}

// Round 12
// 52.008 us; speedup vs baseline: 1.2912x; 1.2912x over previous
//
#include <hip/hip_runtime.h>

typedef __attribute__((ext_vector_type(8))) __bf16 bf16x8;
typedef __attribute__((ext_vector_type(4))) float f32x4;

#define M_ 256
#define N_ 4096
#define K_ 4096
#define SPLITK 4
#define KC (K_ / SPLITK)   // 1024
#define BM 128
#define BN 64
#define BK 32
#define KSTEPS (KC / BK)   // 32
#define NCH 20             // 1KB chunks per K-step: A_hi 8 | A_lo 8 | B 4
#define LDSBUF 20480       // bytes per buffer
#define DEPTH 4            // pipeline depth (3 batches in flight)

// Tiled operand layout: 1KB bf16 tile = 16 rows x 32 k; tile(rt,kt) index
// rt*128+kt; slot lane = (row&15)+16*((k>>3)&3), elem = k&7.
// Producers write in output order (coalesced); every global_load_lds reads
// one contiguous 1KB (lane*16B), zero scatter, zero LDS bank conflicts.

// ---------- helpers ----------

__device__ __forceinline__ unsigned short f2bf(float f) {
  unsigned int u = __builtin_bit_cast(unsigned int, f);
  u += 0x7fffu + ((u >> 16) & 1u);
  return (unsigned short)(u >> 16);
}

__device__ __forceinline__ void async16(const void* g, void* l) {
  __builtin_amdgcn_global_load_lds(
      (const __attribute__((address_space(1))) unsigned int*)g,
      (__attribute__((address_space(3))) unsigned int*)l, 16, 0, 0);
}

__device__ __forceinline__ float lsq1(float y, float a, float s) {
  float yc = fminf(fmaxf(y, -a), a);
  return rintf(yc / s) * s;
}

// per-wave counted vmcnt: waves 0-3 stage 3 chunks/batch, waves 4-7 stage 2
template <int VH, int VL>
__device__ __forceinline__ void waitv(int wave) {
  if (wave < 4) asm volatile("s_waitcnt vmcnt(%0)" ::"n"(VH) : "memory");
  else          asm volatile("s_waitcnt vmcnt(%0)" ::"n"(VL) : "memory");
}

// ---------- K1: fused producer (verified R7 arithmetic — DO NOT TOUCH) ----------
// blocks [0, NQB): lattice-quantize W -> zq (bf16 bits, tiled slot order).
//   z dot: f32 UNFUSED mul+add, sequential ascending — bit-matches XLA:CPU ref.
// blocks [NQB, NQB+NXB): xg = x_blocks @ G^T -> bf16 hi/lo (tiled layout).

#define NQB ((N_ * K_ / 8) / 256)  // 8192
#define NXB ((M_ * K_ / 8) / 256)  // 512

__global__ __launch_bounds__(256) void k_prep(const float* __restrict__ W,
                                              const float* __restrict__ theta,
                                              const float* __restrict__ Ginv,
                                              const float* __restrict__ x,
                                              const float* __restrict__ G,
                                              unsigned short* __restrict__ zq,
                                              unsigned short* __restrict__ hi,
                                              unsigned short* __restrict__ lo,
                                              int kTheta) {
  __shared__ float Ms[64];
  const int tid = threadIdx.x;
  const bool isQ = blockIdx.x < NQB;
  if (tid < 64) Ms[tid] = isQ ? Ginv[tid] : G[tid];
  __syncthreads();

  if (isQ) {
    const int s = blockIdx.x * 256 + tid;       // output 16B slot
    const int lane6 = s & 63;
    const int tile = s >> 6;
    const int o  = ((tile >> 7) << 4) + (lane6 & 15);   // W row
    const int kb = ((tile & 127) << 2) + (lane6 >> 4);  // 8-elt k-block
    const float4* wp = (const float4*)(W + ((size_t)o << 12) + ((size_t)kb << 3));
    const float4 w0 = wp[0], w1 = wp[1];
    float sc = 0.f;
    for (int t = 0; t < kTheta; ++t) sc += theta[o * kTheta + t];
    sc /= (float)kTheta;
    const float wsv[8] = {w0.x * sc, w0.y * sc, w0.z * sc, w0.w * sc,
                          w1.x * sc, w1.y * sc, w1.z * sc, w1.w * sc};
    unsigned int packed[4] = {0u, 0u, 0u, 0u};
    const unsigned long long lut = 0x3F800000BF80C000ull;  // idx 0..3 -> -2,-1,0,+1 (bf16)
#pragma unroll
    for (int i = 0; i < 8; ++i) {
      float t = 0.f;
#pragma unroll
      for (int j = 0; j < 8; ++j)
        t = __fadd_rn(t, __fmul_rn(wsv[j], Ms[j * 8 + i]));  // unfused, sequential
      const int zi = (int)rintf(t);
      const int idx = (zi + 2) & 3;
      const unsigned int h = (unsigned int)((lut >> (idx * 16)) & 0xFFFFull);
      packed[i >> 1] |= h << ((i & 1) * 16);
    }
    *(uint4*)(zq + ((size_t)s << 3)) = make_uint4(packed[0], packed[1], packed[2], packed[3]);
  } else {
    const int s = (blockIdx.x - NQB) * 256 + tid;
    const int lane6 = s & 63;
    const int tile = s >> 6;
    const int m  = ((tile >> 7) << 4) + (lane6 & 15);
    const int kb = ((tile & 127) << 2) + (lane6 >> 4);
    const float4* xp = (const float4*)(x + ((size_t)m << 12) + ((size_t)kb << 3));
    const float4 a0 = xp[0], a1 = xp[1];
    float xv[8] = {a0.x, a0.y, a0.z, a0.w, a1.x, a1.y, a1.z, a1.w};
    unsigned int ph[4] = {0u, 0u, 0u, 0u}, pl[4] = {0u, 0u, 0u, 0u};
#pragma unroll
    for (int i = 0; i < 8; ++i) {
      float t = 0.f;
#pragma unroll
      for (int j = 0; j < 8; ++j) t = fmaf(xv[j], Ms[i * 8 + j], t);
      const unsigned short hb = f2bf(t);
      const float hf = __builtin_bit_cast(float, (unsigned int)hb << 16);
      const unsigned short lb = f2bf(t - hf);
      ph[i >> 1] |= ((unsigned int)hb) << ((i & 1) * 16);
      pl[i >> 1] |= ((unsigned int)lb) << ((i & 1) * 16);
    }
    *(uint4*)(hi + ((size_t)s << 3)) = make_uint4(ph[0], ph[1], ph[2], ph[3]);
    *(uint4*)(lo + ((size_t)s << 3)) = make_uint4(pl[0], pl[1], pl[2], pl[3]);
  }
}

// ---------- K2: split-K GEMM, 4-deep counted-vmcnt pipeline (T3/T4) ----------
// 512 thr = 8 waves (4m x 2n), tile 128x64, BK=32, SPLITK=4.
// 4 x 20KB LDS buffers; prologue issues batches 0..2; per step:
//   waitv (own oldest batch landed) -> raw s_barrier -> issue batch ks+3 into
//   buf[(ks-1)&3] (just freed: its reads retired before this barrier) ->
//   ds_read + MFMA on buf[ks&3].  NO vmcnt(0) drain in the loop.
// Tail peeled with exact waits. Per-accumulator MFMA k-order (ascending k32,
// hi-then-lo) identical to verified r3-r11 -> partials bit-identical.

__global__ __launch_bounds__(512, 4) void k_gemm(const unsigned short* __restrict__ xgh,
                                                 const unsigned short* __restrict__ xgl,
                                                 const unsigned short* __restrict__ z,
                                                 float* __restrict__ part) {
  __shared__ uint4 smem4[DEPTH * LDSBUF / 16];  // 80KB
  char* smem = (char*)smem4;

  const int tid = threadIdx.x;
  const int lane = tid & 63, wave = tid >> 6;
  const int wr = wave >> 1, wc = wave & 1;   // wave grid 4m x 2n
  const int b = blockIdx.x;
  const int mt = b & 1;
  const int sk = (b >> 1) & 3;
  const int nt = b >> 3;                     // 0..63
  const int k0t = sk * (KC / 32);            // base k-tile index
  const int rowa16 = mt * (BM / 16);
  const int rowb16 = nt * (BN / 16);
  const int lrow = lane & 15, lkg = lane >> 4;

  // 20 chunks: c 0..7 = A_hi tile c, 8..15 = A_lo tile c-8, 16..19 = B tile c-16.
  // wave w stages chunks {w, w+8, w+16 (w<4 only)}.
  const unsigned short* src[3];
  unsigned int ldso[3];
#pragma unroll
  for (int ci = 0; ci < 3; ++ci) {
    const int c = ci * 8 + wave;
    if (c < NCH) {
      const unsigned short* P;
      int rt;
      if (c < 8)       { P = xgh; rt = rowa16 + c; }
      else if (c < 16) { P = xgl; rt = rowa16 + (c - 8); }
      else             { P = z;   rt = rowb16 + (c - 16); }
      src[ci] = P + (((size_t)(rt * 128 + k0t)) << 9) + lane * 8;
      ldso[ci] = (unsigned int)c * 1024u;
    } else {
      src[ci] = nullptr;
      ldso[ci] = 0;
    }
  }
  const int nchunk = (wave < 4) ? 3 : 2;

  f32x4 acc[2][2] = {};

  // stage batch kb into buf[kb&3]
  auto issue = [&](int kb) {
    const int wo = (kb & (DEPTH - 1)) * LDSBUF;
    for (int ci = 0; ci < nchunk; ++ci)
      async16(src[ci] + (size_t)kb * 512, smem + wo + ldso[ci]);
  };
  // compute on buf[ks&3]
  auto compute = [&](int ks) {
    const int cur = (ks & (DEPTH - 1)) * LDSBUF;
    bf16x8 bfr[2], ah[2], al[2];
#pragma unroll
    for (int nf = 0; nf < 2; ++nf)
      bfr[nf] = *(const bf16x8*)(smem + cur + (16 + wc * 2 + nf) * 1024 + lane * 16);
#pragma unroll
    for (int mf = 0; mf < 2; ++mf) {
      ah[mf] = *(const bf16x8*)(smem + cur + (wr * 2 + mf) * 1024 + lane * 16);
      al[mf] = *(const bf16x8*)(smem + cur + (8 + wr * 2 + mf) * 1024 + lane * 16);
    }
#pragma unroll
    for (int mf = 0; mf < 2; ++mf)
#pragma unroll
      for (int nf = 0; nf < 2; ++nf) {
        acc[mf][nf] = __builtin_amdgcn_mfma_f32_16x16x32_bf16(ah[mf], bfr[nf], acc[mf][nf], 0, 0, 0);
        acc[mf][nf] = __builtin_amdgcn_mfma_f32_16x16x32_bf16(al[mf], bfr[nf], acc[mf][nf], 0, 0, 0);
      }
  };

  // prologue: batches 0..2 in flight
  issue(0); issue(1); issue(2);

  for (int ks = 0; ks < KSTEPS - 2; ++ks) {
    waitv<6, 4>(wave);                 // own batch[ks] landed (2 batches may remain in flight)
    __builtin_amdgcn_s_barrier();      // all waves' batch[ks] landed; buf[(ks-1)&3] reads retired
    if (ks + 3 < KSTEPS) issue(ks + 3);
    compute(ks);
  }
  waitv<3, 2>(wave);                   // batch[KSTEPS-2] landed (1 in flight)
  __builtin_amdgcn_s_barrier();
  compute(KSTEPS - 2);
  waitv<0, 0>(wave);                   // batch[KSTEPS-1] landed
  __builtin_amdgcn_s_barrier();
  compute(KSTEPS - 1);

  // C/D layout (m89-verified): col = lane&15, row = (lane>>4)*4 + reg
  float* pb = part + (size_t)sk * (M_ * N_);
  const int row_a = mt * BM, row_b = nt * BN;
#pragma unroll
  for (int mf = 0; mf < 2; ++mf)
#pragma unroll
    for (int nf = 0; nf < 2; ++nf)
#pragma unroll
      for (int r = 0; r < 4; ++r) {
        const int m = row_a + wr * 32 + mf * 16 + lkg * 4 + r;
        const int n = row_b + wc * 32 + nf * 16 + lrow;
        pb[(size_t)m * N_ + n] = acc[mf][nf][r];
      }
}

// ---------- K3: reduce 4 split-K partials + bias + LSQ epilogue (R7 verbatim) ----------

__global__ __launch_bounds__(256) void k_epi(const float* __restrict__ part,
                                             const float* __restrict__ bias,
                                             const float* __restrict__ alpha,
                                             float* __restrict__ out) {
  const int i4 = blockIdx.x * 256 + threadIdx.x;  // over M_*N_/4
  const size_t off = (size_t)i4 * 4;
  const float4 p0 = *(const float4*)(part + off);
  const float4 p1 = *(const float4*)(part + (size_t)1 * M_ * N_ + off);
  const float4 p2 = *(const float4*)(part + (size_t)2 * M_ * N_ + off);
  const float4 p3 = *(const float4*)(part + (size_t)3 * M_ * N_ + off);
  const int n = (int)(off & (N_ - 1));
  const float4 bv = *(const float4*)(bias + n);
  const float a = fmaxf(alpha[0], 0.f) + 1e-8f;
  const float s = a / 127.0f;
  float4 o;
  o.x = lsq1(((p0.x + p1.x) + p2.x) + p3.x + bv.x, a, s);
  o.y = lsq1(((p0.y + p1.y) + p2.y) + p3.y + bv.y, a, s);
  o.z = lsq1(((p0.z + p1.z) + p2.z) + p3.z + bv.z, a, s);
  o.w = lsq1(((p0.w + p1.w) + p2.w) + p3.w + bv.w, a, s);
  *(float4*)(out + off) = o;
}

// ---------- launch ----------

extern "C" void kernel_launch(void* const* d_in, const int* in_sizes, int n_in,
                              void* d_out, int out_size, void* d_ws, size_t ws_size,
                              hipStream_t stream) {
  const float* x     = (const float*)d_in[0];
  const float* W     = (const float*)d_in[1];
  const float* bias  = (const float*)d_in[2];
  const float* theta = (const float*)d_in[3];
  const float* alpha = (const float*)d_in[4];
  const float* G     = (const float*)d_in[5];
  const float* Ginv  = (const float*)d_in[6];
  float* out = (float*)d_out;

  const int O = in_sizes[2];           // 4096
  const int kTheta = in_sizes[3] / O;  // 1

  // ws layout: zq bf16 tiled 32MB | xg_hi 2MB | xg_lo 2MB | partials [4][M][N] 16MB
  char* ws = (char*)d_ws;
  unsigned short* zq  = (unsigned short*)ws;
  unsigned short* xgh = (unsigned short*)(ws + 33554432);
  unsigned short* xgl = (unsigned short*)(ws + 35651584);
  float* part = (float*)(ws + 37748736);
  if (ws_size < 54525952) return;  // guard: need 52MB scratch

  k_prep<<<NQB + NXB, 256, 0, stream>>>(W, theta, Ginv, x, G, zq, xgh, xgl, kTheta);
  k_gemm<<<2 * SPLITK * 64, 512, 0, stream>>>(xgh, xgl, zq, part);
  k_epi<<<(M_ * N_ / 4) / 256, 256, 0, stream>>>(part, bias, alpha, out);
}

// Round 13
// 49.247 us; speedup vs baseline: 1.3636x; 1.0561x over previous
//
#include <hip/hip_runtime.h>

typedef __attribute__((ext_vector_type(8))) __bf16 bf16x8;
typedef __attribute__((ext_vector_type(4))) float f32x4;

#define M_ 256
#define N_ 4096
#define K_ 4096
#define SPLITK 4
#define KC (K_ / SPLITK)   // 1024
#define BM 128
#define BN 64
#define BK 32
#define KSTEPS (KC / BK)   // 32
#define NCH 20
#define LDSBUF 20480

// Tiled operand layout: 1KB bf16 tile = 16 rows x 32 k; tile(rt,kt) index
// rt*128+kt; slot lane = (row&15)+16*((k>>3)&3), elem = k&7.
// xgh/xgl: 16B/slot bf16 (async16-staged). z2: 2B/slot = 8x2-bit indices,
// decoded in-GEMM to the SAME bf16 bits the zq path staged.

// ---------- helpers ----------

__device__ __forceinline__ unsigned short f2bf(float f) {
  unsigned int u = __builtin_bit_cast(unsigned int, f);
  u += 0x7fffu + ((u >> 16) & 1u);
  return (unsigned short)(u >> 16);
}

__device__ __forceinline__ void async16(const void* g, void* l) {
  __builtin_amdgcn_global_load_lds(
      (const __attribute__((address_space(1))) unsigned int*)g,
      (__attribute__((address_space(3))) unsigned int*)l, 16, 0, 0);
}

__device__ __forceinline__ float lsq1(float y, float a, float s) {
  float yc = fminf(fmaxf(y, -a), a);
  return rintf(yc / s) * s;
}

// bf16 bit patterns for z_mod = idx-2: idx 0->-2, 1->-1, 2->0, 3->+1
#define ZLUT 0x3F800000BF80C000ull

// decode 8x2-bit word -> 16B (8 bf16), elem order ascending
__device__ __forceinline__ uint4 zdec(unsigned int w) {
  unsigned int d[4];
#pragma unroll
  for (int p = 0; p < 4; ++p) {
    const unsigned int lo = (unsigned int)((ZLUT >> (((w >> (4 * p)) & 3u) * 16)) & 0xFFFFull);
    const unsigned int hi = (unsigned int)((ZLUT >> (((w >> (4 * p + 2)) & 3u) * 16)) & 0xFFFFull);
    d[p] = lo | (hi << 16);
  }
  return make_uint4(d[0], d[1], d[2], d[3]);
}

// ---------- K1: fused producer ----------
// blocks [0, NQB): lattice-quantize W -> z2 (2-bit indices, tiled slot order).
//   z dot: f32 UNFUSED mul+add, sequential ascending — matches XLA:CPU's
//   fmul/fadd chain. CRITICAL: `#pragma clang fp contract(off)` — HIP's
//   __fmul_rn/__fadd_rn are plain ops and -ffp-contract=fast MAY fuse them
//   (root cause of the R1/R9/R10 absmax=0.701 failures: a few z boundary
//   flips from fused fmaf). The pragma guarantees separate rn mul + rn add.
// blocks [NQB, NQB+NXB): xg = x_blocks @ G^T -> bf16 hi/lo (tiled layout).

#define NQB ((N_ * K_ / 8) / 256)  // 8192
#define NXB ((M_ * K_ / 8) / 256)  // 512

__global__ __launch_bounds__(256) void k_prep(const float* __restrict__ W,
                                              const float* __restrict__ theta,
                                              const float* __restrict__ Ginv,
                                              const float* __restrict__ x,
                                              const float* __restrict__ G,
                                              unsigned short* __restrict__ z2,
                                              unsigned short* __restrict__ hi,
                                              unsigned short* __restrict__ lo,
                                              int kTheta) {
  __shared__ float Ms[64];
  const int tid = threadIdx.x;
  const bool isQ = blockIdx.x < NQB;
  if (tid < 64) Ms[tid] = isQ ? Ginv[tid] : G[tid];
  __syncthreads();

  if (isQ) {
#pragma clang fp contract(off)
    const int s = blockIdx.x * 256 + tid;       // output slot
    const int lane6 = s & 63;
    const int tile = s >> 6;
    const int o  = ((tile >> 7) << 4) + (lane6 & 15);   // W row
    const int kb = ((tile & 127) << 2) + (lane6 >> 4);  // 8-elt k-block
    const float4* wp = (const float4*)(W + ((size_t)o << 12) + ((size_t)kb << 3));
    const float4 w0 = wp[0], w1 = wp[1];
    float sc = 0.f;
    for (int t = 0; t < kTheta; ++t) sc += theta[o * kTheta + t];
    sc /= (float)kTheta;
    const float wsv[8] = {w0.x * sc, w0.y * sc, w0.z * sc, w0.w * sc,
                          w1.x * sc, w1.y * sc, w1.z * sc, w1.w * sc};
    unsigned int word = 0u;
#pragma unroll
    for (int i = 0; i < 8; ++i) {
      float t = 0.f;
#pragma unroll
      for (int j = 0; j < 8; ++j)
        t = t + wsv[j] * Ms[j * 8 + i];   // contract(off): separate rn mul + rn add
      const int zi = (int)rintf(t);
      word |= (unsigned int)((zi + 2) & 3) << (2 * i);
    }
    z2[s] = (unsigned short)word;
  } else {
    const int s = (blockIdx.x - NQB) * 256 + tid;
    const int lane6 = s & 63;
    const int tile = s >> 6;
    const int m  = ((tile >> 7) << 4) + (lane6 & 15);
    const int kb = ((tile & 127) << 2) + (lane6 >> 4);
    const float4* xp = (const float4*)(x + ((size_t)m << 12) + ((size_t)kb << 3));
    const float4 a0 = xp[0], a1 = xp[1];
    float xv[8] = {a0.x, a0.y, a0.z, a0.w, a1.x, a1.y, a1.z, a1.w};
    unsigned int ph[4] = {0u, 0u, 0u, 0u}, pl[4] = {0u, 0u, 0u, 0u};
#pragma unroll
    for (int i = 0; i < 8; ++i) {
      float t = 0.f;
#pragma unroll
      for (int j = 0; j < 8; ++j) t = fmaf(xv[j], Ms[i * 8 + j], t);
      const unsigned short hb = f2bf(t);
      const float hf = __builtin_bit_cast(float, (unsigned int)hb << 16);
      const unsigned short lb = f2bf(t - hf);
      ph[i >> 1] |= ((unsigned int)hb) << ((i & 1) * 16);
      pl[i >> 1] |= ((unsigned int)lb) << ((i & 1) * 16);
    }
    *(uint4*)(hi + ((size_t)s << 3)) = make_uint4(ph[0], ph[1], ph[2], ph[3]);
    *(uint4*)(lo + ((size_t)s << 3)) = make_uint4(pl[0], pl[1], pl[2], pl[3]);
  }
}

// ---------- K2: split-K GEMM (R7 schedule; B staged via z2 decode) ----------
// 512 thr = 8 waves (4m x 2n), tile 128x64, BK=32, 2-barrier double buffer.
// A: async16 contiguous-1KB; wave w stages A_hi tile w + A_lo tile w.
// B: waves 0-3 load z2 word (pipelined 1 step ahead), zdec, ds_write_b128
//    into chunk 16+wave — same bytes/slots the old async16-from-zq wrote.
// Per-accumulator MFMA k-order (ascending k32, hi-then-lo) = verified r3-r12.

__global__ __launch_bounds__(512, 4) void k_gemm(const unsigned short* __restrict__ xgh,
                                                 const unsigned short* __restrict__ xgl,
                                                 const unsigned short* __restrict__ z2,
                                                 float* __restrict__ part) {
  __shared__ uint4 smem4[2 * LDSBUF / 16];  // 40KB double buffer
  char* smem = (char*)smem4;

  const int tid = threadIdx.x;
  const int lane = tid & 63, wave = tid >> 6;
  const int wr = wave >> 1, wc = wave & 1;   // wave grid 4m x 2n
  const int b = blockIdx.x;
  const int mt = b & 1;
  const int sk = (b >> 1) & 3;
  const int nt = b >> 3;                     // 0..63
  const int k0t = sk * (KC / 32);
  const int rowa16 = mt * (BM / 16);
  const int rowb16 = nt * (BN / 16);
  const int lrow = lane & 15, lkg = lane >> 4;

  // A chunks: ci=0 -> A_hi tile `wave` (chunk wave); ci=1 -> A_lo tile `wave` (chunk wave+8)
  const unsigned short* asrc[2];
  int aldo[2];
#pragma unroll
  for (int ci = 0; ci < 2; ++ci) {
    const unsigned short* P = (ci == 0) ? xgh : xgl;
    asrc[ci] = P + (((size_t)((rowa16 + wave) * 128 + k0t)) << 9) + lane * 8;
    aldo[ci] = (ci * 8 + wave) * 1024;
  }
  // B role (waves 0-3): B tile rowb16+wave -> chunk 16+wave
  const bool brole = (wave < 4);
  const unsigned short* zsrc = nullptr;
  int bofs = 0;
  if (brole) {
    zsrc = z2 + (((size_t)((rowb16 + wave) * 128 + k0t)) << 6) + lane;
    bofs = (16 + wave) * 1024 + lane * 16;
  }

  f32x4 acc[2][2] = {};

  // prologue: stage step 0 into buffer 0; preload zw for step 1
  unsigned int zw = 0;
#pragma unroll
  for (int ci = 0; ci < 2; ++ci) async16(asrc[ci], smem + aldo[ci]);
  if (brole) {
    zw = zsrc[0];
    *(uint4*)(smem + bofs) = zdec(zw);
    zw = zsrc[64];  // step 1 word
  }
  __syncthreads();

  for (int ks = 0; ks < KSTEPS; ++ks) {
    const int cur = (ks & 1) * LDSBUF;
    const int nxt = LDSBUF - cur;
    if (ks + 1 < KSTEPS) {
#pragma unroll
      for (int ci = 0; ci < 2; ++ci)
        async16(asrc[ci] + (size_t)(ks + 1) * 512, smem + nxt + aldo[ci]);
      if (brole) {
        *(uint4*)(smem + nxt + bofs) = zdec(zw);
        if (ks + 2 < KSTEPS) zw = zsrc[(size_t)(ks + 2) * 64];
      }
    }

    bf16x8 bfr[2], ah[2], al[2];
#pragma unroll
    for (int nf = 0; nf < 2; ++nf)
      bfr[nf] = *(const bf16x8*)(smem + cur + (16 + wc * 2 + nf) * 1024 + lane * 16);
#pragma unroll
    for (int mf = 0; mf < 2; ++mf) {
      ah[mf] = *(const bf16x8*)(smem + cur + (wr * 2 + mf) * 1024 + lane * 16);
      al[mf] = *(const bf16x8*)(smem + cur + (8 + wr * 2 + mf) * 1024 + lane * 16);
    }
#pragma unroll
    for (int mf = 0; mf < 2; ++mf)
#pragma unroll
      for (int nf = 0; nf < 2; ++nf) {
        acc[mf][nf] = __builtin_amdgcn_mfma_f32_16x16x32_bf16(ah[mf], bfr[nf], acc[mf][nf], 0, 0, 0);
        acc[mf][nf] = __builtin_amdgcn_mfma_f32_16x16x32_bf16(al[mf], bfr[nf], acc[mf][nf], 0, 0, 0);
      }
    __syncthreads();  // drains vmcnt+lgkm: stage above targets NEXT buffer
  }

  // C/D layout (m89-verified): col = lane&15, row = (lane>>4)*4 + reg
  float* pb = part + (size_t)sk * (M_ * N_);
  const int row_a = mt * BM, row_b = nt * BN;
#pragma unroll
  for (int mf = 0; mf < 2; ++mf)
#pragma unroll
    for (int nf = 0; nf < 2; ++nf)
#pragma unroll
      for (int r = 0; r < 4; ++r) {
        const int m = row_a + wr * 32 + mf * 16 + lkg * 4 + r;
        const int n = row_b + wc * 32 + nf * 16 + lrow;
        pb[(size_t)m * N_ + n] = acc[mf][nf][r];
      }
}

// ---------- K3: reduce 4 split-K partials + bias + LSQ epilogue ----------

__global__ __launch_bounds__(256) void k_epi(const float* __restrict__ part,
                                             const float* __restrict__ bias,
                                             const float* __restrict__ alpha,
                                             float* __restrict__ out) {
  const int i4 = blockIdx.x * 256 + threadIdx.x;  // over M_*N_/4
  const size_t off = (size_t)i4 * 4;
  const float4 p0 = *(const float4*)(part + off);
  const float4 p1 = *(const float4*)(part + (size_t)1 * M_ * N_ + off);
  const float4 p2 = *(const float4*)(part + (size_t)2 * M_ * N_ + off);
  const float4 p3 = *(const float4*)(part + (size_t)3 * M_ * N_ + off);
  const int n = (int)(off & (N_ - 1));
  const float4 bv = *(const float4*)(bias + n);
  const float a = fmaxf(alpha[0], 0.f) + 1e-8f;
  const float s = a / 127.0f;
  float4 o;
  o.x = lsq1(((p0.x + p1.x) + p2.x) + p3.x + bv.x, a, s);
  o.y = lsq1(((p0.y + p1.y) + p2.y) + p3.y + bv.y, a, s);
  o.z = lsq1(((p0.z + p1.z) + p2.z) + p3.z + bv.z, a, s);
  o.w = lsq1(((p0.w + p1.w) + p2.w) + p3.w + bv.w, a, s);
  *(float4*)(out + off) = o;
}

// ---------- launch ----------

extern "C" void kernel_launch(void* const* d_in, const int* in_sizes, int n_in,
                              void* d_out, int out_size, void* d_ws, size_t ws_size,
                              hipStream_t stream) {
  const float* x     = (const float*)d_in[0];
  const float* W     = (const float*)d_in[1];
  const float* bias  = (const float*)d_in[2];
  const float* theta = (const float*)d_in[3];
  const float* alpha = (const float*)d_in[4];
  const float* G     = (const float*)d_in[5];
  const float* Ginv  = (const float*)d_in[6];
  float* out = (float*)d_out;

  const int O = in_sizes[2];           // 4096
  const int kTheta = in_sizes[3] / O;  // 1

  // ws layout: xg_hi 2MB | xg_lo 2MB | z2 4MB | partials [4][M][N] 16MB
  char* ws = (char*)d_ws;
  unsigned short* xgh = (unsigned short*)ws;
  unsigned short* xgl = (unsigned short*)(ws + 2097152);
  unsigned short* z2  = (unsigned short*)(ws + 4194304);
  float* part = (float*)(ws + 8388608);
  if (ws_size < 25165824) return;  // guard: need 24MB scratch

  k_prep<<<NQB + NXB, 256, 0, stream>>>(W, theta, Ginv, x, G, z2, xgh, xgl, kTheta);
  k_gemm<<<2 * SPLITK * 64, 512, 0, stream>>>(xgh, xgl, z2, part);
  k_epi<<<(M_ * N_ / 4) / 256, 256, 0, stream>>>(part, bias, alpha, out);
}